// Round 2
// baseline (133.322 us; speedup 1.0000x reference)
//
#include <hip/hip_runtime.h>

#define MAX_ITEMS 100000
constexpr int B = 4096;
constexpr int D = 512;
constexpr long long ACT_ELEMS  = (long long)B * D;               // 2097152
constexpr long long HIST_ELEMS = (long long)(MAX_ITEMS + 1) * D; // 51200512
// d_out layout: [0, ACT) activations, [ACT] loss, [ACT+1, ACT+1+HIST) new_history
// new_history base is float index ACT+1 -> 4B-aligned only; floats [3..) of a
// history row group are 16B-aligned on the DST side.

// ---------------------------------------------------------------------------
// Kernel 1a: activations -> out[0..ACT), both sides 16B aligned, KU-way ILP.
// Also handles the 4 stray scalar elements of the history copy (head 0,1,2
// and tail HIST_ELEMS-1).
// ---------------------------------------------------------------------------
template <int KU>
__global__ void copy_act_kernel(const float* __restrict__ act,
                                const float* __restrict__ hist,
                                float* __restrict__ out) {
    constexpr long long NA4 = ACT_ELEMS / 4; // 524288, divisible by 256*KU
    const long long chunk = (long long)blockDim.x * KU;
    for (long long c = blockIdx.x; c * chunk < NA4; c += gridDim.x) {
        const long long g0 = c * chunk + threadIdx.x;
        float4 v[KU];
        #pragma unroll
        for (int k = 0; k < KU; ++k)
            v[k] = reinterpret_cast<const float4*>(act)[g0 + (long long)k * blockDim.x];
        #pragma unroll
        for (int k = 0; k < KU; ++k)
            reinterpret_cast<float4*>(out)[g0 + (long long)k * blockDim.x] = v[k];
    }
    if (blockIdx.x == 0 && threadIdx.x == 0) {
        float* outh = out + ACT_ELEMS + 1;
        outh[0] = hist[0];
        outh[1] = hist[1];
        outh[2] = hist[2];
        outh[HIST_ELEMS - 1] = hist[HIST_ELEMS - 1];
    }
}

// ---------------------------------------------------------------------------
// Kernel 1b: history -> out[ACT+1..). DST-aligned float4 stores; SRC is
// misaligned by one float -> 4 scalar loads per group. KU-way ILP: all
// 4*KU loads issued before the KU stores.
// ---------------------------------------------------------------------------
template <int KU>
__global__ void copy_hist_kernel(const float* __restrict__ hist,
                                 float* __restrict__ out) {
    constexpr long long NG = (HIST_ELEMS - 3) / 4; // 12800127 float4 groups
    float* __restrict__ outh = out + ACT_ELEMS + 1;
    const long long chunk = (long long)blockDim.x * KU;
    for (long long c = blockIdx.x; c * chunk < NG; c += gridDim.x) {
        const long long g0 = c * chunk + threadIdx.x;
        float4 v[KU];
        #pragma unroll
        for (int k = 0; k < KU; ++k) {
            const long long g = g0 + (long long)k * blockDim.x;
            if (g < NG) {
                const long long sb = 3 + 4 * g;
                v[k].x = hist[sb + 0];
                v[k].y = hist[sb + 1];
                v[k].z = hist[sb + 2];
                v[k].w = hist[sb + 3];
            }
        }
        #pragma unroll
        for (int k = 0; k < KU; ++k) {
            const long long g = g0 + (long long)k * blockDim.x;
            if (g < NG)
                *reinterpret_cast<float4*>(outh + 3 + 4 * g) = v[k];
        }
    }
}

// ---------------------------------------------------------------------------
// Kernel 2: one wave per sample. Gather old row (ORIGINAL history input),
// wave-reduce sum of squared diff -> partial[s], scatter EMA update into
// new_history with atomicAdd (duplicate ids must accumulate).
// ---------------------------------------------------------------------------
__global__ void update_kernel(const float* __restrict__ act,
                              const float* __restrict__ hist,
                              const int* __restrict__ samples,
                              float* __restrict__ out,
                              float* __restrict__ partial) {
    const int s    = blockIdx.x;
    const int lane = threadIdx.x; // 0..63

    const int id = samples[s];
    const bool active = (id > 0) && (id < MAX_ITEMS);

    float sumsq = 0.0f;
    if (active) {
        const float* __restrict__ arow = act  + (long long)s  * D;
        const float* __restrict__ orow = hist + (long long)id * D;
        float* __restrict__ newh = out + ACT_ELEMS + 1 + (long long)id * D;

        #pragma unroll
        for (int k = 0; k < 2; ++k) {
            const int e = (lane + k * 64) * 4; // 128 float4 per row
            const float4 a = *reinterpret_cast<const float4*>(arow + e);
            const float4 o = *reinterpret_cast<const float4*>(orow + e);
            const float dx = a.x - o.x;
            const float dy = a.y - o.y;
            const float dz = a.z - o.z;
            const float dw = a.w - o.w;
            sumsq += dx * dx + dy * dy + dz * dz + dw * dw;
            atomicAdd(newh + e + 0, 0.1f * dx);
            atomicAdd(newh + e + 1, 0.1f * dy);
            atomicAdd(newh + e + 2, 0.1f * dz);
            atomicAdd(newh + e + 3, 0.1f * dw);
        }
    }
    #pragma unroll
    for (int off = 32; off; off >>= 1)
        sumsq += __shfl_down(sumsq, off);
    if (lane == 0) partial[s] = sumsq;
}

// ---------------------------------------------------------------------------
// Kernel 3: deterministic single-block reduction of 4096 partials -> loss.
// ---------------------------------------------------------------------------
__global__ void loss_kernel(const float* __restrict__ partial,
                            const int* __restrict__ iters,
                            float* __restrict__ out) {
    __shared__ float sm[256];
    const int t = threadIdx.x;
    float s = 0.0f;
    for (int i = t; i < B; i += 256) s += partial[i];
    sm[t] = s;
    __syncthreads();
    #pragma unroll
    for (int w = 128; w; w >>= 1) {
        if (t < w) sm[t] += sm[t + w];
        __syncthreads();
    }
    if (t == 0) {
        const float it = (float)iters[0];
        const float wr = (float)(1.0 / 1000.0)   * it;
        const float cr = (float)(1.0 / 100000.0) * it;
        const float weight = 0.1f * wr / (1.0f + wr) / (1.0f + cr);
        out[ACT_ELEMS] = (sm[0] / (float)D / (float)B) * weight;
    }
}

extern "C" void kernel_launch(void* const* d_in, const int* in_sizes, int n_in,
                              void* d_out, int out_size, void* d_ws, size_t ws_size,
                              hipStream_t stream) {
    const float* act     = (const float*)d_in[0];
    const float* hist    = (const float*)d_in[1];
    const int*   samples = (const int*)d_in[2];
    const int*   iters   = (const int*)d_in[3];
    float* out     = (float*)d_out;
    float* partial = (float*)d_ws; // B*4 = 16 KiB scratch

    copy_hist_kernel<8><<<2048, 256, 0, stream>>>(hist, out);
    copy_act_kernel<8><<<256, 256, 0, stream>>>(act, hist, out);
    update_kernel<<<B, 64, 0, stream>>>(act, hist, samples, out, partial);
    loss_kernel<<<1, 256, 0, stream>>>(partial, iters, out);
}